// Round 6
// baseline (477.700 us; speedup 1.0000x reference)
//
#include <hip/hip_runtime.h>

#define S_LEN 2048
#define HID_DIM 4096
#define NH 32
#define NKV 8
#define HD 128
#define QKV_N 6144
#define SCALE_F 0.08838834764831845f

typedef unsigned short u16;
typedef __attribute__((ext_vector_type(8))) __bf16 bf16x8;
typedef __attribute__((ext_vector_type(4))) float f32x4;

__device__ __forceinline__ u16 f2bf(float f) {
  unsigned u = __float_as_uint(f);
  return (u16)((u + 0x7fffu + ((u >> 16) & 1u)) >> 16);
}
__device__ __forceinline__ float bf2f(u16 v) {
  return __uint_as_float((unsigned)v << 16);
}

__device__ __forceinline__ void gl_lds16(const u16* g, u16* l) {
  __builtin_amdgcn_global_load_lds(
      (const __attribute__((address_space(1))) unsigned int*)g,
      (__attribute__((address_space(3))) unsigned int*)l, 16, 0, 0);
}

// ---------------- elementwise / layout kernels ----------------

__global__ void k_f32_to_bf16(const float* __restrict__ in, u16* __restrict__ out, long n4) {
  long i = (long)blockIdx.x * blockDim.x + threadIdx.x;
  if (i >= n4) return;
  float4 v = ((const float4*)in)[i];
  ushort4 o;
  o.x = f2bf(v.x); o.y = f2bf(v.y); o.z = f2bf(v.z); o.w = f2bf(v.w);
  ((ushort4*)out)[i] = o;
}

// out[c][r] = (bf16) in[r][c], 64x64 tiles, 256 thr; float2 reads, ushort2 writes.
__global__ void k_tr64(const float* __restrict__ in, u16* __restrict__ out,
                       int ld_in, int ld_out, long in_bs, long out_bs) {
  __shared__ float tile[64][65];
  const float* A = in + (long)blockIdx.z * in_bs;
  u16* O = out + (long)blockIdx.z * out_bs;
  int r0 = blockIdx.y * 64, c0 = blockIdx.x * 64;
  int tx = threadIdx.x & 31, ty = threadIdx.x >> 5;  // tx 0..31, ty 0..7
#pragma unroll
  for (int i = 0; i < 8; i++) {
    int r = ty + 8 * i;
    float2 v = *(const float2*)&A[(long)(r0 + r) * ld_in + c0 + 2 * tx];
    tile[r][2 * tx] = v.x;
    tile[r][2 * tx + 1] = v.y;
  }
  __syncthreads();
#pragma unroll
  for (int i = 0; i < 8; i++) {
    int c = ty + 8 * i;
    ushort2 o;
    o.x = f2bf(tile[2 * tx][c]);
    o.y = f2bf(tile[2 * tx + 1][c]);
    *(ushort2*)&O[(long)(c0 + c) * ld_out + r0 + 2 * tx] = o;
  }
}

__global__ void k_norm_to_bc(const float* __restrict__ norm, u16* __restrict__ bc) {
  int h = blockIdx.y;
  int i = blockIdx.x * 256 + threadIdx.x;  // 0..16383
  bc[(long)h * 32768 + 16384 + i] = f2bf(norm[(long)h * 16384 + i]);
}

// ---------------- GEMM v5: C[M,N] = A[M,K]bf16 @ Bt[N,K]bf16^T ----------------
// BM=BN=128, BK=32, 256 thr (4 waves 2x2, per-wave 64x64). Triple-buffered LDS
// (3 x 16 KiB = 48 KiB) -> 3 blocks/CU. Stages issued 2 tiles ahead, counted
// vmcnt(4) + one raw s_barrier per K-tile. Swizzle: 16B-colblock
// blk = cb ^ ((row>>1)&3) on pre-swizzled global source and ds_read.

__global__ __launch_bounds__(256, 3) void k_gemm5(
    const u16* __restrict__ A, const u16* __restrict__ Bt, void* __restrict__ Cv,
    int K, int ldc, long strideA, long strideB, long strideC, int bmodB, int obf) {
  __shared__ __align__(16) u16 lds[3 * 8192];  // per buf: A[128][32]=4096 u16, B[128][32]=4096
  const int bz = blockIdx.z;
  const u16* Ap = A + (long)bz * strideA;
  const u16* Bp = Bt + (long)(bz % bmodB) * strideB;
  const long coff = (long)bz * strideC;

  // XCD-bijective block swizzle over x*y (all call sites have nwg % 8 == 0)
  const int gx = gridDim.x;
  const int nwg = gx * gridDim.y;
  int id = blockIdx.y * gx + blockIdx.x;
  if (!(nwg & 7)) { int q = nwg >> 3; id = (id & 7) * q + (id >> 3); }
  const int n0 = (id % gx) * 128, m0 = (id / gx) * 128;

  const int tid = threadIdx.x, wid = tid >> 6, lane = tid & 63;
  const int l15 = lane & 15, lhi = lane >> 4;
  const int wm = wid >> 1, wn = wid & 1;  // per-wave 64 x 64

  // stage source bases (pre-swizzled global, u16 element offsets)
  const int swc = ((lane & 3) ^ ((lane >> 3) & 3)) * 8;
  const long gA0 = (long)(m0 + (lane >> 2)) * K + swc;
  const long gB0 = (long)(n0 + (lane >> 2)) * K + swc;

  // ds_read fragment bases (swizzled); +q*512 per 16-row step
  const int swr = (lhi ^ ((l15 >> 1) & 3)) * 8;
  const int abase = (wm * 64 + l15) * 32 + swr;
  const int bbase = 4096 + (wn * 64 + l15) * 32 + swr;

  const int KT = K >> 5;
  f32x4 acc[4][4];
#pragma unroll
  for (int i = 0; i < 4; i++)
#pragma unroll
    for (int j = 0; j < 4; j++) acc[i][j] = (f32x4){0.f, 0.f, 0.f, 0.f};

  // prologue: stage tiles 0 and 1 (4 wave-loads each)
#pragma unroll
  for (int tt = 0; tt < 2; tt++) {
    u16* sb = &lds[tt * 8192];
    const long ko = (long)tt * 32;
    gl_lds16(Ap + gA0 + (long)(wid * 16) * K + ko, &sb[wid * 512]);
    gl_lds16(Ap + gA0 + (long)((wid + 4) * 16) * K + ko, &sb[(wid + 4) * 512]);
    gl_lds16(Bp + gB0 + (long)(wid * 16) * K + ko, &sb[4096 + wid * 512]);
    gl_lds16(Bp + gB0 + (long)((wid + 4) * 16) * K + ko, &sb[4096 + (wid + 4) * 512]);
  }
  asm volatile("s_waitcnt vmcnt(4)" ::: "memory");
  __builtin_amdgcn_s_barrier();
  asm volatile("" ::: "memory");

  int b = 0;
  for (int t = 0; t < KT; ++t) {
    const int sbi = (b + 2 >= 3) ? (b - 1) : (b + 2);
    const u16* lb = &lds[b * 8192];
    u16* sb = &lds[sbi * 8192];
    const bool dst = (t + 2) < KT;
    const long ko = (long)(t + 2) * 32;

    bf16x8 bfr[4];
#pragma unroll
    for (int nq = 0; nq < 4; nq++) bfr[nq] = *(const bf16x8*)&lb[bbase + nq * 512];

#pragma unroll
    for (int ph = 0; ph < 4; ph++) {
      bf16x8 a0 = *(const bf16x8*)&lb[abase + ph * 512];
      if (dst) {
        if (ph == 0) gl_lds16(Ap + gA0 + (long)(wid * 16) * K + ko, &sb[wid * 512]);
        else if (ph == 1) gl_lds16(Ap + gA0 + (long)((wid + 4) * 16) * K + ko, &sb[(wid + 4) * 512]);
        else if (ph == 2) gl_lds16(Bp + gB0 + (long)(wid * 16) * K + ko, &sb[4096 + wid * 512]);
        else gl_lds16(Bp + gB0 + (long)((wid + 4) * 16) * K + ko, &sb[4096 + (wid + 4) * 512]);
      }
      __builtin_amdgcn_s_setprio(1);
#pragma unroll
      for (int nq = 0; nq < 4; nq++)
        acc[ph][nq] = __builtin_amdgcn_mfma_f32_16x16x32_bf16(a0, bfr[nq], acc[ph][nq], 0, 0, 0);
      __builtin_amdgcn_s_setprio(0);
    }

    if (t + 1 < KT) {
      if (dst)
        asm volatile("s_waitcnt vmcnt(4)" ::: "memory");
      else
        asm volatile("s_waitcnt vmcnt(0)" ::: "memory");
      __builtin_amdgcn_s_barrier();
      asm volatile("" ::: "memory");
    }
    b = (b + 1 >= 3) ? 0 : (b + 1);
  }

#pragma unroll
  for (int mi = 0; mi < 4; mi++)
#pragma unroll
    for (int ni = 0; ni < 4; ni++)
#pragma unroll
      for (int j = 0; j < 4; j++) {
        long row = m0 + wm * 64 + mi * 16 + lhi * 4 + j;
        long col = n0 + wn * 64 + ni * 16 + l15;
        if (obf)
          ((u16*)Cv)[coff + row * ldc + col] = f2bf(acc[mi][ni][j]);
        else
          ((float*)Cv)[coff + row * ldc + col] = acc[mi][ni][j];
      }
}

// ---------------- fused qn + rope (trig computed in-kernel) ----------------

__global__ void k_qnrope(const float* __restrict__ qkv, const int* __restrict__ pos,
                         u16* __restrict__ qnb, u16* __restrict__ qrb,
                         u16* __restrict__ knb, u16* __restrict__ krb,
                         float* __restrict__ knf) {
  int s = blockIdx.x, y = blockIdx.y, l = threadIdx.x;  // 64 threads
  bool isq = y < NH;
  int h = isq ? y : y - NH;
  const float* row = qkv + (long)s * QKV_N + (isq ? h * HD : HID_DIM + h * HD);
  float x0 = row[l], x1 = row[l + 64];
  float f0 = x0 > 0.f ? x0 + 1.f : __expf(x0);
  float f1 = x1 > 0.f ? x1 + 1.f : __expf(x1);
  float sum = f0 + f1;
#pragma unroll
  for (int m = 32; m >= 1; m >>= 1) sum += __shfl_xor(sum, m);
  float inv = 1.f / (sum + 1e-8f);
  float y0 = f0 * inv, y1 = f1 * inv;
  long o = ((long)h * S_LEN + s) * HD;
  float p = (float)pos[s];
  float ang = p * expf(-(float)l * (9.210340371976184f / 64.0f));
  float c = cosf(ang), sn = sinf(ang);
  u16 r0 = f2bf(x0 * c - x1 * sn), r1 = f2bf(x1 * c + x0 * sn);
  if (isq) {
    qnb[o + l] = f2bf(y0); qnb[o + l + 64] = f2bf(y1);
    qrb[o + l] = r0; qrb[o + l + 64] = r1;
  } else {
    knb[o + l] = f2bf(y0); knb[o + l + 64] = f2bf(y1);
    knf[o + l] = y0; knf[o + l + 64] = y1;
    krb[o + l] = r0; krb[o + l + 64] = r1;
  }
}

// ---------------- U = v - v_ret ----------------

__global__ void k_uvret(const u16* __restrict__ rawk, const float* __restrict__ qkv,
                        float* __restrict__ U) {
  int s = blockIdx.x, h = blockIdx.y, e = threadIdx.x;  // 128 threads
  long base = ((long)h * S_LEN + s) * 256;
  float num = bf2f(rawk[base + e]), den = bf2f(rawk[base + 128 + e]);
  U[((long)h * S_LEN + s) * HD + e] =
      qkv[(long)s * QKV_N + HID_DIM + NKV * HD + h * HD + e] - num / (den + 1e-8f);
}

// ---------------- flash attention v3: pipelined K/V staging ----------------
// Double-buffered K/V (2 x 32 KiB). Stage(t+1) issued right after tile t's
// barrier; vmcnt(0) deferred to the NEXT tile top (covered by tile t compute).

__global__ __launch_bounds__(256, 2) void k_flash3(
    const u16* __restrict__ qr, const u16* __restrict__ kr,
    const u16* __restrict__ vt, float* __restrict__ attn) {
  __shared__ u16 KV[2][16384];      // per buf: Ks[64][128] then Vs[128][64], swizzled
  __shared__ u16 Ps[4][16 * 64];    // per-wave [q 16][kv 64] swizzled
  const int bx = blockIdx.x, h = blockIdx.y;
  const int hk = h >> 2;  // GROUPS=4, repeat_interleave
  const int tid = threadIdx.x, wid = tid >> 6, lane = tid & 63;
  const int l15 = lane & 15, lhi = lane >> 4;
  const u16* qbase = qr + (long)h * S_LEN * HD;
  const u16* kb0 = kr + (long)hk * S_LEN * HD;
  const u16* vb0 = vt + (long)hk * HD * S_LEN;
  float* ob = attn + (long)h * S_LEN * HD;
  u16* P = Ps[wid];

  // stage offsets (computed once)
  int kr_r[4], kr_sc[4], vr_r[4], vr_sc[4];
#pragma unroll
  for (int it = 0; it < 4; it++) {
    int chunk = it * 4 + wid;
    kr_r[it] = chunk * 4 + (lane >> 4);
    kr_sc[it] = ((lane & 15) * 8) ^ ((kr_r[it] & 7) * 8);
    vr_r[it] = chunk * 8 + (lane >> 3);
    vr_sc[it] = ((lane & 7) * 8) ^ ((vr_r[it] & 7) * 8);
  }

  for (int si = 0; si < 2; si++) {
    const int s = si ? (31 - bx) : bx;
    const int qs = s * 64 + wid * 16;
    bf16x8 aq[4];
#pragma unroll
    for (int kc = 0; kc < 4; kc++)
      aq[kc] = *(const bf16x8*)&qbase[(long)(qs + l15) * HD + kc * 32 + lhi * 8];
    f32x4 accO[8];
#pragma unroll
    for (int i = 0; i < 8; i++) accO[i] = (f32x4){0.f, 0.f, 0.f, 0.f};
    float rs[4] = {0.f, 0.f, 0.f, 0.f};

    if (si) __syncthreads();  // prior segment done reading buffers
    // prologue: stage tile 0 into buf 0
    {
      u16* Kb = KV[0];
#pragma unroll
      for (int it = 0; it < 4; it++)
        gl_lds16(kb0 + (long)kr_r[it] * HD + kr_sc[it], &Kb[(it * 4 + wid) * 512]);
#pragma unroll
      for (int it = 0; it < 4; it++)
        gl_lds16(vb0 + (long)vr_r[it] * S_LEN + vr_sc[it], &Kb[8192 + (it * 4 + wid) * 512]);
    }
    int cur = 0;

    for (int t = 0; t <= s; t++) {
      asm volatile("s_waitcnt vmcnt(0)" ::: "memory");
      __syncthreads();
      if (t < s) {
        u16* Kb = KV[cur ^ 1];
        const long kt = (long)(t + 1) * 64;
#pragma unroll
        for (int it = 0; it < 4; it++)
          gl_lds16(kb0 + (kt + kr_r[it]) * HD + kr_sc[it], &Kb[(it * 4 + wid) * 512]);
#pragma unroll
        for (int it = 0; it < 4; it++)
          gl_lds16(vb0 + (long)vr_r[it] * S_LEN + kt + vr_sc[it], &Kb[8192 + (it * 4 + wid) * 512]);
      }
      const u16* Ks = KV[cur];
      const u16* Vs = Ks + 8192;

      // QK^T : 16 MFMA
      f32x4 accS[4];
#pragma unroll
      for (int i = 0; i < 4; i++) accS[i] = (f32x4){0.f, 0.f, 0.f, 0.f};
#pragma unroll
      for (int ni = 0; ni < 4; ni++) {
        int row = ni * 16 + l15;
#pragma unroll
        for (int kc = 0; kc < 4; kc++) {
          bf16x8 bk = *(const bf16x8*)&Ks[row * 128 + ((kc * 32 + lhi * 8) ^ ((row & 7) * 8))];
          accS[ni] = __builtin_amdgcn_mfma_f32_16x16x32_bf16(aq[kc], bk, accS[ni], 0, 0, 0);
        }
      }
      const bool diag = (t == s);
#pragma unroll
      for (int ni = 0; ni < 4; ni++) {
        int col = t * 64 + ni * 16 + l15;
#pragma unroll
        for (int j = 0; j < 4; j++) {
          int row = qs + lhi * 4 + j;
          float p = (!diag || col <= row) ? __expf(accS[ni][j] * SCALE_F) : 0.f;
          rs[j] += p;
          int pr = lhi * 4 + j;
          P[pr * 64 + ((ni * 16 + l15) ^ ((pr & 7) * 8))] = f2bf(p);
        }
      }
      asm volatile("s_waitcnt lgkmcnt(0)" ::: "memory");
      __builtin_amdgcn_sched_barrier(0);
      // PV : 16 MFMA
      bf16x8 ap[2];
#pragma unroll
      for (int ks = 0; ks < 2; ks++)
        ap[ks] = *(const bf16x8*)&P[l15 * 64 + ((ks * 32 + lhi * 8) ^ ((l15 & 7) * 8))];
#pragma unroll
      for (int nj = 0; nj < 8; nj++) {
        int row = nj * 16 + l15;
#pragma unroll
        for (int ks = 0; ks < 2; ks++) {
          bf16x8 bv = *(const bf16x8*)&Vs[row * 64 + ((ks * 32 + lhi * 8) ^ ((row & 7) * 8))];
          accO[nj] = __builtin_amdgcn_mfma_f32_16x16x32_bf16(ap[ks], bv, accO[nj], 0, 0, 0);
        }
      }
      cur ^= 1;
    }
#pragma unroll
    for (int j = 0; j < 4; j++) {
      float v = rs[j];
      v += __shfl_xor(v, 1);
      v += __shfl_xor(v, 2);
      v += __shfl_xor(v, 4);
      v += __shfl_xor(v, 8);
      rs[j] = 1.f / v;
    }
#pragma unroll
    for (int nj = 0; nj < 8; nj++)
#pragma unroll
      for (int j = 0; j < 4; j++)
        ob[(long)(qs + lhi * 4 + j) * HD + nj * 16 + l15] = accO[nj][j] * rs[j];
  }
}

// ---------------- combine ----------------

__global__ void k_combine(const u16* __restrict__ rawq, const float* __restrict__ attn,
                          const float* __restrict__ beta, u16* __restrict__ comb) {
  int s = blockIdx.x, h = blockIdx.y, d = threadIdx.x;  // 128 threads
  float g = 1.f / (1.f + __expf(-beta[0]));
  long b = ((long)h * S_LEN + s) * 256;
  float mo = bf2f(rawq[b + d]) / (bf2f(rawq[b + 128 + d]) + 1e-8f);
  float ao = attn[((long)h * S_LEN + s) * HD + d];
  comb[(long)s * HID_DIM + h * HD + d] = f2bf(g * mo + (1.f - g) * ao);
}

// ---------------- delta-rule memory / norm updates (f32 exact path) ----------------

__global__ void k_delta_part(const float* __restrict__ knf, const float* __restrict__ U,
                             float* __restrict__ dpart) {
  int d0 = blockIdx.x * 16, h = blockIdx.y, c = blockIdx.z, e = threadIdx.x;
  const float* kh = knf + (long)h * S_LEN * HD + (long)c * 512 * HD;
  const float* Uh = U + (long)h * S_LEN * HD + (long)c * 512 * HD;
  float a[16];
#pragma unroll
  for (int d = 0; d < 16; d++) a[d] = 0.f;
  for (int s = 0; s < 512; s++) {
    float u = Uh[(long)s * HD + e];
    const float* kr = &kh[(long)s * HD + d0];
#pragma unroll
    for (int d = 0; d < 16; d++) a[d] += kr[d] * u;
  }
  long ob = (long)c * (NKV * HD * HD) + (long)h * HD * HD + (long)d0 * HD + e;
#pragma unroll
  for (int d = 0; d < 16; d++) dpart[ob + (long)d * HD] = a[d];
}

__global__ void k_delta_reduce(const float* __restrict__ dpart, const float* __restrict__ mem,
                               float* __restrict__ outmem) {
  long i = (long)blockIdx.x * 256 + threadIdx.x;  // 131072
  const long N = (long)NKV * HD * HD;
  float a = dpart[i] + dpart[N + i] + dpart[2 * N + i] + dpart[3 * N + i];
  outmem[i] = mem[i] + a;
}

__global__ void k_norm_part(const float* __restrict__ knf, float* __restrict__ npart) {
  int c = blockIdx.x, h = blockIdx.y, j = threadIdx.x;  // 16 x 8, 128 thr
  const float* kh = knf + (long)h * S_LEN * HD + (long)c * 128 * HD;
  float a = 0.f;
  for (int s = 0; s < 128; s++) a += kh[(long)s * HD + j];
  npart[((long)c * NKV + h) * HD + j] = a;
}

__global__ void k_norm_write(const float* __restrict__ npart, const float* __restrict__ norm,
                             float* __restrict__ outn) {
  // grid (NKV, 64), 256 thr: 2 rows of 128 per block
  int h = blockIdx.x, j = threadIdx.x & 127;
  int r = blockIdx.y * 2 + (threadIdx.x >> 7);
  float cs = 0.f;
#pragma unroll
  for (int c = 0; c < 16; c++) cs += npart[((long)c * NKV + h) * HD + j];
  long o = (long)h * HD * HD + (long)r * HD + j;
  outn[o] = norm[o] + cs;
}

// ---------------- host ----------------
// Aliased arena (stream-serialized), same map as rounds 2-5 (peak 154.5 MiB).

extern "C" void kernel_launch(void* const* d_in, const int* in_sizes, int n_in,
                              void* d_out, int out_size, void* d_ws, size_t ws_size,
                              hipStream_t stream) {
  const float* hs = (const float*)d_in[0];
  const int* pos = (const int*)d_in[1];
  const float* wq = (const float*)d_in[2];
  const float* wk = (const float*)d_in[3];
  const float* wv = (const float*)d_in[4];
  const float* wo = (const float*)d_in[5];
  const float* memf = (const float*)d_in[6];
  const float* normf = (const float*)d_in[7];
  const float* beta = (const float*)d_in[8];
  (void)in_sizes; (void)n_in; (void)out_size; (void)ws_size;

  float* out = (float*)d_out;
  float* out_mem = out + (long)S_LEN * HID_DIM;
  float* out_norm = out_mem + NKV * HD * HD;

  const size_t MB = 1u << 20;
  char* w = (char*)d_ws;
  u16* hsb    = (u16*)(w + 0);
  u16* qnb    = (u16*)(w + 0);
  u16* comb   = (u16*)(w + 0);
  float* dpart= (float*)(w + 0);
  float* npart= (float*)(w + 2 * MB);
  u16* wT6    = (u16*)(w + 16 * MB);
  u16* rawq   = (u16*)(w + 16 * MB);
  u16* woT    = (u16*)(w + 16 * MB);
  u16* rawk   = (u16*)(w + 48 * MB);
  u16* bc     = (u16*)(w + 57 * MB);
  u16* vtb    = (u16*)(w + 57 * MB + 512 * 1024);
  float* qkvf = (float*)(w + 66 * MB + 512 * 1024);
  float* attn = (float*)(w + 66 * MB + 512 * 1024);
  float* Ub   = (float*)(w + 114 * MB + 512 * 1024);
  float* knf  = (float*)(w + 122 * MB + 512 * 1024);
  u16* qrb    = (u16*)(w + 130 * MB + 512 * 1024);
  u16* krb    = (u16*)(w + 146 * MB + 512 * 1024);
  u16* knb    = (u16*)(w + 150 * MB + 512 * 1024);

  // --- A: conversions + fused QKV projection ---
  k_f32_to_bf16<<<dim3((S_LEN * HID_DIM / 4 + 255) / 256), dim3(256), 0, stream>>>(
      hs, hsb, (long)(S_LEN * HID_DIM / 4));
  k_tr64<<<dim3(64, 64, 1), dim3(256), 0, stream>>>(
      wq, wT6, HID_DIM, HID_DIM, 0L, 0L);
  k_tr64<<<dim3(16, 64, 1), dim3(256), 0, stream>>>(
      wk, wT6 + (long)HID_DIM * HID_DIM, 1024, HID_DIM, 0L, 0L);
  k_tr64<<<dim3(16, 64, 1), dim3(256), 0, stream>>>(
      wv, wT6 + (long)(HID_DIM + 1024) * HID_DIM, 1024, HID_DIM, 0L, 0L);
  k_gemm5<<<dim3(QKV_N / 128, S_LEN / 128, 1), dim3(256), 0, stream>>>(
      hsb, wT6, qkvf, HID_DIM, QKV_N, 0L, 0L, 0L, 1, 0);

  // --- D: qn + rope fused ---
  k_qnrope<<<dim3(S_LEN, NH + NKV), dim3(64), 0, stream>>>(
      qkvf, pos, qnb, qrb, knb, krb, knf);

  // --- E: V^T per kv head; bc = [mem^T | norm] bf16 ---
  k_tr64<<<dim3(2, 32, NKV), dim3(256), 0, stream>>>(
      qkvf + HID_DIM + NKV * HD, vtb, QKV_N, S_LEN, 128L, (long)(HD * S_LEN));
  k_tr64<<<dim3(2, 2, NKV), dim3(256), 0, stream>>>(
      memf, bc, HD, HD, (long)(HD * HD), (long)(256 * HD));
  k_norm_to_bc<<<dim3(64, NKV), dim3(256), 0, stream>>>(normf, bc);

  // --- F: retrieval raws (batched, bf16 out) ---
  k_gemm5<<<dim3(2, 16, NH), dim3(256), 0, stream>>>(
      qnb, bc, rawq, HD, 256, (long)(S_LEN * HD), (long)(256 * HD),
      (long)(S_LEN * 256), NKV, 1);
  k_gemm5<<<dim3(2, 16, NKV), dim3(256), 0, stream>>>(
      knb, bc, rawk, HD, 256, (long)(S_LEN * HD), (long)(256 * HD),
      (long)(S_LEN * 256), NKV, 1);

  // --- G: U = v - v_ret ---
  k_uvret<<<dim3(S_LEN, NKV), dim3(128), 0, stream>>>(rawk, qkvf, Ub);

  // --- H: attention ---
  k_flash3<<<dim3(16, NH), dim3(256), 0, stream>>>(qrb, krb, vtb, attn);

  // --- I: combine ---
  k_combine<<<dim3(S_LEN, NH), dim3(128), 0, stream>>>(rawq, attn, beta, comb);

  // --- J: wo^T; output projection ---
  k_tr64<<<dim3(64, 64, 1), dim3(256), 0, stream>>>(
      wo, woT, HID_DIM, HID_DIM, 0L, 0L);
  k_gemm5<<<dim3(HID_DIM / 128, S_LEN / 128, 1), dim3(256), 0, stream>>>(
      comb, woT, out, HID_DIM, HID_DIM, 0L, 0L, 0L, 1, 0);

  // --- K: memory / norm updates ---
  k_delta_part<<<dim3(8, NKV, 4), dim3(128), 0, stream>>>(knf, Ub, dpart);
  k_delta_reduce<<<dim3(512), dim3(256), 0, stream>>>(dpart, memf, out_mem);
  k_norm_part<<<dim3(16, NKV), dim3(128), 0, stream>>>(knf, npart);
  k_norm_write<<<dim3(NKV, 64), dim3(256), 0, stream>>>(npart, normf, out_norm);
}

// Round 7
// 447.230 us; speedup vs baseline: 1.0681x; 1.0681x over previous
//
#include <hip/hip_runtime.h>

#define S_LEN 2048
#define HID_DIM 4096
#define NH 32
#define NKV 8
#define HD 128
#define QKV_N 6144
#define SCALE_F 0.08838834764831845f

typedef unsigned short u16;
typedef __attribute__((ext_vector_type(8))) __bf16 bf16x8;
typedef __attribute__((ext_vector_type(4))) float f32x4;

__device__ __forceinline__ u16 f2bf(float f) {
  unsigned u = __float_as_uint(f);
  return (u16)((u + 0x7fffu + ((u >> 16) & 1u)) >> 16);
}
__device__ __forceinline__ float bf2f(u16 v) {
  return __uint_as_float((unsigned)v << 16);
}

__device__ __forceinline__ void gl_lds16(const u16* g, u16* l) {
  __builtin_amdgcn_global_load_lds(
      (const __attribute__((address_space(1))) unsigned int*)g,
      (__attribute__((address_space(3))) unsigned int*)l, 16, 0, 0);
}

// ---------------- elementwise / layout kernels ----------------

__global__ void k_f32_to_bf16(const float* __restrict__ in, u16* __restrict__ out, long n4) {
  long i = (long)blockIdx.x * blockDim.x + threadIdx.x;
  if (i >= n4) return;
  float4 v = ((const float4*)in)[i];
  ushort4 o;
  o.x = f2bf(v.x); o.y = f2bf(v.y); o.z = f2bf(v.z); o.w = f2bf(v.w);
  ((ushort4*)out)[i] = o;
}

// out[c][r] = (bf16) in[r][c], 64x64 tiles, 256 thr; float2 reads, ushort2 writes.
__global__ void k_tr64(const float* __restrict__ in, u16* __restrict__ out,
                       int ld_in, int ld_out, long in_bs, long out_bs) {
  __shared__ float tile[64][65];
  const float* A = in + (long)blockIdx.z * in_bs;
  u16* O = out + (long)blockIdx.z * out_bs;
  int r0 = blockIdx.y * 64, c0 = blockIdx.x * 64;
  int tx = threadIdx.x & 31, ty = threadIdx.x >> 5;  // tx 0..31, ty 0..7
#pragma unroll
  for (int i = 0; i < 8; i++) {
    int r = ty + 8 * i;
    float2 v = *(const float2*)&A[(long)(r0 + r) * ld_in + c0 + 2 * tx];
    tile[r][2 * tx] = v.x;
    tile[r][2 * tx + 1] = v.y;
  }
  __syncthreads();
#pragma unroll
  for (int i = 0; i < 8; i++) {
    int c = ty + 8 * i;
    ushort2 o;
    o.x = f2bf(tile[2 * tx][c]);
    o.y = f2bf(tile[2 * tx + 1][c]);
    *(ushort2*)&O[(long)(c0 + c) * ld_out + r0 + 2 * tx] = o;
  }
}

__global__ void k_norm_to_bc(const float* __restrict__ norm, u16* __restrict__ bc) {
  int h = blockIdx.y;
  int i = blockIdx.x * 256 + threadIdx.x;  // 0..16383
  bc[(long)h * 32768 + 16384 + i] = f2bf(norm[(long)h * 16384 + i]);
}

// ---------------- GEMM v6: C[M,N] = A[M,K]bf16 @ Bt[N,K]bf16^T ----------------
// BM=128 BN=256 BK=64, 512 thr (8 waves = 2M x 4N, 64x64 per wave).
// Triple-buffered LDS (3 x 48 KiB = 144 KiB), stages issued 2 K-tiles ahead,
// counted vmcnt(6) + one raw s_barrier per K-tile. Per tile: 2 phases of
// {ds_read frags | 3 stage issues | s_barrier | setprio+16 MFMA+setprio}.
// Swizzle: 16B-colblock blk ^= (row&7) on pre-swizzled source and ds_read.
// Block mapping: XCD-contiguous chunks, m-fastest (per-XCD K-slice fits L2).

__global__ __launch_bounds__(512, 2) void k_gemm6(
    const u16* __restrict__ A, const u16* __restrict__ Bt, void* __restrict__ Cv,
    int K, int ldc, long strideA, long strideB, long strideC, int bmodB, int obf) {
  __shared__ __align__(16) u16 lds[3 * 24576];  // per buf: A[128][64]=8192 u16, B[256][64]=16384
  const int bz = blockIdx.z;
  const u16* Ap = A + (long)bz * strideA;
  const u16* Bp = Bt + (long)(bz % bmodB) * strideB;
  const long coff = (long)bz * strideC;

  const int gx = gridDim.x, gy = gridDim.y;
  const int nwg = gx * gy;
  int id = blockIdx.y * gx + blockIdx.x;
  if (!(nwg & 7)) { int q = nwg >> 3; id = (id & 7) * q + (id >> 3); }
  const int m0 = (id % gy) * 128;   // m-fastest within XCD chunk
  const int n0 = (id / gy) * 256;

  const int tid = threadIdx.x, wid = tid >> 6, lane = tid & 63;
  const int l15 = lane & 15, lhi = lane >> 4;
  const int wm = wid >> 2, wn = wid & 3;  // per-wave 64 x 64

  // stage: per load, thread covers row ld*64 + tid/8, 16B-colblock tid&7 (pre-swizzled)
  const int srow = tid >> 3, scb = tid & 7;
  const int ssw = (scb ^ (srow & 7)) * 8;
  const long gA = (long)(m0 + srow) * K + ssw;   // + ld*64*K + kt
  const long gB = (long)(n0 + srow) * K + ssw;

  // ds_read swizzle: block = (kk*4+lhi) ^ (l15&7); row&7 == l15&7 (rows are x16)
  const int swk = (lhi ^ (l15 & 7)) * 8;
  const int arow = (wm * 64 + l15) * 64;          // + mi*1024 (+kk via swk^32)
  const int brow = 8192 + (wn * 64 + l15) * 64;   // + ni*1024

  const int KT = K >> 6;
  f32x4 acc[4][4];
#pragma unroll
  for (int i = 0; i < 4; i++)
#pragma unroll
    for (int j = 0; j < 4; j++) acc[i][j] = (f32x4){0.f, 0.f, 0.f, 0.f};

  // prologue: stage K-tiles 0 and 1 (6 loads each: 4 B + 2 A)
#pragma unroll
  for (int tt = 0; tt < 2; tt++) {
    const long kt = (long)tt * 64;
    u16* sb = &lds[tt * 24576];
#pragma unroll
    for (int ld = 0; ld < 4; ld++)
      gl_lds16(Bp + gB + (long)(ld * 64) * K + kt, &sb[8192 + ld * 4096 + wid * 512]);
#pragma unroll
    for (int ld = 0; ld < 2; ld++)
      gl_lds16(Ap + gA + (long)(ld * 64) * K + kt, &sb[ld * 4096 + wid * 512]);
  }
  asm volatile("s_waitcnt vmcnt(6)" ::: "memory");
  __builtin_amdgcn_s_barrier();
  asm volatile("" ::: "memory");

  int b = 0;
  for (int t = 0; t < KT; ++t) {
    const int sbi = (b + 2 >= 3) ? (b - 1) : (b + 2);
    const u16* lb = &lds[b * 24576];
    u16* sb = &lds[sbi * 24576];
    const bool dst = (t + 2) < KT;
    const long kt = (long)(t + 2) * 64;

    // ---- phase 0: read all B frags + A[0..1]; stage B0..B2; 16 MFMA (mi 0,1) ----
    bf16x8 Bf[4][2], Af0[2][2];
#pragma unroll
    for (int ni = 0; ni < 4; ni++) {
      Bf[ni][0] = *(const bf16x8*)&lb[brow + ni * 1024 + swk];
      Bf[ni][1] = *(const bf16x8*)&lb[brow + ni * 1024 + (swk ^ 32)];
    }
#pragma unroll
    for (int mi = 0; mi < 2; mi++) {
      Af0[mi][0] = *(const bf16x8*)&lb[arow + mi * 1024 + swk];
      Af0[mi][1] = *(const bf16x8*)&lb[arow + mi * 1024 + (swk ^ 32)];
    }
    if (dst) {
      gl_lds16(Bp + gB + kt, &sb[8192 + wid * 512]);
      gl_lds16(Bp + gB + (long)64 * K + kt, &sb[8192 + 4096 + wid * 512]);
      gl_lds16(Bp + gB + (long)128 * K + kt, &sb[8192 + 8192 + wid * 512]);
    }
    __builtin_amdgcn_s_barrier();
    __builtin_amdgcn_s_setprio(1);
#pragma unroll
    for (int mi = 0; mi < 2; mi++)
#pragma unroll
      for (int ni = 0; ni < 4; ni++) {
        acc[mi][ni] = __builtin_amdgcn_mfma_f32_16x16x32_bf16(Af0[mi][0], Bf[ni][0], acc[mi][ni], 0, 0, 0);
        acc[mi][ni] = __builtin_amdgcn_mfma_f32_16x16x32_bf16(Af0[mi][1], Bf[ni][1], acc[mi][ni], 0, 0, 0);
      }
    __builtin_amdgcn_s_setprio(0);

    // ---- phase 1: read A[2..3]; stage B3,A0,A1; 16 MFMA (mi 2,3) ----
    bf16x8 Af1[2][2];
#pragma unroll
    for (int mi = 0; mi < 2; mi++) {
      Af1[mi][0] = *(const bf16x8*)&lb[arow + (mi + 2) * 1024 + swk];
      Af1[mi][1] = *(const bf16x8*)&lb[arow + (mi + 2) * 1024 + (swk ^ 32)];
    }
    if (dst) {
      gl_lds16(Bp + gB + (long)192 * K + kt, &sb[8192 + 12288 + wid * 512]);
      gl_lds16(Ap + gA + kt, &sb[wid * 512]);
      gl_lds16(Ap + gA + (long)64 * K + kt, &sb[4096 + wid * 512]);
    }
    __builtin_amdgcn_s_barrier();
    __builtin_amdgcn_s_setprio(1);
#pragma unroll
    for (int mi = 0; mi < 2; mi++)
#pragma unroll
      for (int ni = 0; ni < 4; ni++) {
        acc[mi + 2][ni] = __builtin_amdgcn_mfma_f32_16x16x32_bf16(Af1[mi][0], Bf[ni][0], acc[mi + 2][ni], 0, 0, 0);
        acc[mi + 2][ni] = __builtin_amdgcn_mfma_f32_16x16x32_bf16(Af1[mi][1], Bf[ni][1], acc[mi + 2][ni], 0, 0, 0);
      }
    __builtin_amdgcn_s_setprio(0);

    // ---- tile boundary: counted wait (never 0 mid-loop) + barrier ----
    if (t + 1 < KT) {
      if (dst)
        asm volatile("s_waitcnt vmcnt(6)" ::: "memory");
      else
        asm volatile("s_waitcnt vmcnt(0)" ::: "memory");
      __builtin_amdgcn_s_barrier();
      asm volatile("" ::: "memory");
    }
    b = (b + 1 >= 3) ? 0 : (b + 1);
  }

#pragma unroll
  for (int mi = 0; mi < 4; mi++)
#pragma unroll
    for (int ni = 0; ni < 4; ni++)
#pragma unroll
      for (int j = 0; j < 4; j++) {
        long row = m0 + wm * 64 + mi * 16 + lhi * 4 + j;
        long col = n0 + wn * 64 + ni * 16 + l15;
        if (obf)
          ((u16*)Cv)[coff + row * ldc + col] = f2bf(acc[mi][ni][j]);
        else
          ((float*)Cv)[coff + row * ldc + col] = acc[mi][ni][j];
      }
}

// ---------------- fused qn + rope (trig computed in-kernel) ----------------

__global__ void k_qnrope(const float* __restrict__ qkv, const int* __restrict__ pos,
                         u16* __restrict__ qnb, u16* __restrict__ qrb,
                         u16* __restrict__ knb, u16* __restrict__ krb,
                         float* __restrict__ knf) {
  int s = blockIdx.x, y = blockIdx.y, l = threadIdx.x;  // 64 threads
  bool isq = y < NH;
  int h = isq ? y : y - NH;
  const float* row = qkv + (long)s * QKV_N + (isq ? h * HD : HID_DIM + h * HD);
  float x0 = row[l], x1 = row[l + 64];
  float f0 = x0 > 0.f ? x0 + 1.f : __expf(x0);
  float f1 = x1 > 0.f ? x1 + 1.f : __expf(x1);
  float sum = f0 + f1;
#pragma unroll
  for (int m = 32; m >= 1; m >>= 1) sum += __shfl_xor(sum, m);
  float inv = 1.f / (sum + 1e-8f);
  float y0 = f0 * inv, y1 = f1 * inv;
  long o = ((long)h * S_LEN + s) * HD;
  float p = (float)pos[s];
  float ang = p * expf(-(float)l * (9.210340371976184f / 64.0f));
  float c = cosf(ang), sn = sinf(ang);
  u16 r0 = f2bf(x0 * c - x1 * sn), r1 = f2bf(x1 * c + x0 * sn);
  if (isq) {
    qnb[o + l] = f2bf(y0); qnb[o + l + 64] = f2bf(y1);
    qrb[o + l] = r0; qrb[o + l + 64] = r1;
  } else {
    knb[o + l] = f2bf(y0); knb[o + l + 64] = f2bf(y1);
    knf[o + l] = y0; knf[o + l + 64] = y1;
    krb[o + l] = r0; krb[o + l + 64] = r1;
  }
}

// ---------------- U = v - v_ret ----------------

__global__ void k_uvret(const u16* __restrict__ rawk, const float* __restrict__ qkv,
                        float* __restrict__ U) {
  int s = blockIdx.x, h = blockIdx.y, e = threadIdx.x;  // 128 threads
  long base = ((long)h * S_LEN + s) * 256;
  float num = bf2f(rawk[base + e]), den = bf2f(rawk[base + 128 + e]);
  U[((long)h * S_LEN + s) * HD + e] =
      qkv[(long)s * QKV_N + HID_DIM + NKV * HD + h * HD + e] - num / (den + 1e-8f);
}

// ---------------- flash attention v3: pipelined K/V staging ----------------

__global__ __launch_bounds__(256, 2) void k_flash3(
    const u16* __restrict__ qr, const u16* __restrict__ kr,
    const u16* __restrict__ vt, float* __restrict__ attn) {
  __shared__ u16 KV[2][16384];      // per buf: Ks[64][128] then Vs[128][64], swizzled
  __shared__ u16 Ps[4][16 * 64];    // per-wave [q 16][kv 64] swizzled
  const int bx = blockIdx.x, h = blockIdx.y;
  const int hk = h >> 2;  // GROUPS=4, repeat_interleave
  const int tid = threadIdx.x, wid = tid >> 6, lane = tid & 63;
  const int l15 = lane & 15, lhi = lane >> 4;
  const u16* qbase = qr + (long)h * S_LEN * HD;
  const u16* kb0 = kr + (long)hk * S_LEN * HD;
  const u16* vb0 = vt + (long)hk * HD * S_LEN;
  float* ob = attn + (long)h * S_LEN * HD;
  u16* P = Ps[wid];

  int kr_r[4], kr_sc[4], vr_r[4], vr_sc[4];
#pragma unroll
  for (int it = 0; it < 4; it++) {
    int chunk = it * 4 + wid;
    kr_r[it] = chunk * 4 + (lane >> 4);
    kr_sc[it] = ((lane & 15) * 8) ^ ((kr_r[it] & 7) * 8);
    vr_r[it] = chunk * 8 + (lane >> 3);
    vr_sc[it] = ((lane & 7) * 8) ^ ((vr_r[it] & 7) * 8);
  }

  for (int si = 0; si < 2; si++) {
    const int s = si ? (31 - bx) : bx;
    const int qs = s * 64 + wid * 16;
    bf16x8 aq[4];
#pragma unroll
    for (int kc = 0; kc < 4; kc++)
      aq[kc] = *(const bf16x8*)&qbase[(long)(qs + l15) * HD + kc * 32 + lhi * 8];
    f32x4 accO[8];
#pragma unroll
    for (int i = 0; i < 8; i++) accO[i] = (f32x4){0.f, 0.f, 0.f, 0.f};
    float rs[4] = {0.f, 0.f, 0.f, 0.f};

    if (si) __syncthreads();
    {
      u16* Kb = KV[0];
#pragma unroll
      for (int it = 0; it < 4; it++)
        gl_lds16(kb0 + (long)kr_r[it] * HD + kr_sc[it], &Kb[(it * 4 + wid) * 512]);
#pragma unroll
      for (int it = 0; it < 4; it++)
        gl_lds16(vb0 + (long)vr_r[it] * S_LEN + vr_sc[it], &Kb[8192 + (it * 4 + wid) * 512]);
    }
    int cur = 0;

    for (int t = 0; t <= s; t++) {
      asm volatile("s_waitcnt vmcnt(0)" ::: "memory");
      __syncthreads();
      if (t < s) {
        u16* Kb = KV[cur ^ 1];
        const long kt = (long)(t + 1) * 64;
#pragma unroll
        for (int it = 0; it < 4; it++)
          gl_lds16(kb0 + (kt + kr_r[it]) * HD + kr_sc[it], &Kb[(it * 4 + wid) * 512]);
#pragma unroll
        for (int it = 0; it < 4; it++)
          gl_lds16(vb0 + (long)vr_r[it] * S_LEN + kt + vr_sc[it], &Kb[8192 + (it * 4 + wid) * 512]);
      }
      const u16* Ks = KV[cur];
      const u16* Vs = Ks + 8192;

      f32x4 accS[4];
#pragma unroll
      for (int i = 0; i < 4; i++) accS[i] = (f32x4){0.f, 0.f, 0.f, 0.f};
#pragma unroll
      for (int ni = 0; ni < 4; ni++) {
        int row = ni * 16 + l15;
#pragma unroll
        for (int kc = 0; kc < 4; kc++) {
          bf16x8 bk = *(const bf16x8*)&Ks[row * 128 + ((kc * 32 + lhi * 8) ^ ((row & 7) * 8))];
          accS[ni] = __builtin_amdgcn_mfma_f32_16x16x32_bf16(aq[kc], bk, accS[ni], 0, 0, 0);
        }
      }
      const bool diag = (t == s);
#pragma unroll
      for (int ni = 0; ni < 4; ni++) {
        int col = t * 64 + ni * 16 + l15;
#pragma unroll
        for (int j = 0; j < 4; j++) {
          int row = qs + lhi * 4 + j;
          float p = (!diag || col <= row) ? __expf(accS[ni][j] * SCALE_F) : 0.f;
          rs[j] += p;
          int pr = lhi * 4 + j;
          P[pr * 64 + ((ni * 16 + l15) ^ ((pr & 7) * 8))] = f2bf(p);
        }
      }
      asm volatile("s_waitcnt lgkmcnt(0)" ::: "memory");
      __builtin_amdgcn_sched_barrier(0);
      bf16x8 ap[2];
#pragma unroll
      for (int ks = 0; ks < 2; ks++)
        ap[ks] = *(const bf16x8*)&P[l15 * 64 + ((ks * 32 + lhi * 8) ^ ((l15 & 7) * 8))];
#pragma unroll
      for (int nj = 0; nj < 8; nj++) {
        int row = nj * 16 + l15;
#pragma unroll
        for (int ks = 0; ks < 2; ks++) {
          bf16x8 bv = *(const bf16x8*)&Vs[row * 64 + ((ks * 32 + lhi * 8) ^ ((row & 7) * 8))];
          accO[nj] = __builtin_amdgcn_mfma_f32_16x16x32_bf16(ap[ks], bv, accO[nj], 0, 0, 0);
        }
      }
      cur ^= 1;
    }
#pragma unroll
    for (int j = 0; j < 4; j++) {
      float v = rs[j];
      v += __shfl_xor(v, 1);
      v += __shfl_xor(v, 2);
      v += __shfl_xor(v, 4);
      v += __shfl_xor(v, 8);
      rs[j] = 1.f / v;
    }
#pragma unroll
    for (int nj = 0; nj < 8; nj++)
#pragma unroll
      for (int j = 0; j < 4; j++)
        ob[(long)(qs + lhi * 4 + j) * HD + nj * 16 + l15] = accO[nj][j] * rs[j];
  }
}

// ---------------- combine ----------------

__global__ void k_combine(const u16* __restrict__ rawq, const float* __restrict__ attn,
                          const float* __restrict__ beta, u16* __restrict__ comb) {
  int s = blockIdx.x, h = blockIdx.y, d = threadIdx.x;  // 128 threads
  float g = 1.f / (1.f + __expf(-beta[0]));
  long b = ((long)h * S_LEN + s) * 256;
  float mo = bf2f(rawq[b + d]) / (bf2f(rawq[b + 128 + d]) + 1e-8f);
  float ao = attn[((long)h * S_LEN + s) * HD + d];
  comb[(long)s * HID_DIM + h * HD + d] = f2bf(g * mo + (1.f - g) * ao);
}

// ---------------- delta-rule memory / norm updates (f32 exact path) ----------------

__global__ void k_delta_part(const float* __restrict__ knf, const float* __restrict__ U,
                             float* __restrict__ dpart) {
  int d0 = blockIdx.x * 16, h = blockIdx.y, c = blockIdx.z, e = threadIdx.x;
  const float* kh = knf + (long)h * S_LEN * HD + (long)c * 512 * HD;
  const float* Uh = U + (long)h * S_LEN * HD + (long)c * 512 * HD;
  float a[16];
#pragma unroll
  for (int d = 0; d < 16; d++) a[d] = 0.f;
  for (int s = 0; s < 512; s++) {
    float u = Uh[(long)s * HD + e];
    const float* kr = &kh[(long)s * HD + d0];
#pragma unroll
    for (int d = 0; d < 16; d++) a[d] += kr[d] * u;
  }
  long ob = (long)c * (NKV * HD * HD) + (long)h * HD * HD + (long)d0 * HD + e;
#pragma unroll
  for (int d = 0; d < 16; d++) dpart[ob + (long)d * HD] = a[d];
}

__global__ void k_delta_reduce(const float* __restrict__ dpart, const float* __restrict__ mem,
                               float* __restrict__ outmem) {
  long i = (long)blockIdx.x * 256 + threadIdx.x;  // 131072
  const long N = (long)NKV * HD * HD;
  float a = dpart[i] + dpart[N + i] + dpart[2 * N + i] + dpart[3 * N + i];
  outmem[i] = mem[i] + a;
}

__global__ void k_norm_part(const float* __restrict__ knf, float* __restrict__ npart) {
  int c = blockIdx.x, h = blockIdx.y, j = threadIdx.x;  // 16 x 8, 128 thr
  const float* kh = knf + (long)h * S_LEN * HD + (long)c * 128 * HD;
  float a = 0.f;
  for (int s = 0; s < 128; s++) a += kh[(long)s * HD + j];
  npart[((long)c * NKV + h) * HD + j] = a;
}

__global__ void k_norm_write(const float* __restrict__ npart, const float* __restrict__ norm,
                             float* __restrict__ outn) {
  // grid (NKV, 64), 256 thr: 2 rows of 128 per block
  int h = blockIdx.x, j = threadIdx.x & 127;
  int r = blockIdx.y * 2 + (threadIdx.x >> 7);
  float cs = 0.f;
#pragma unroll
  for (int c = 0; c < 16; c++) cs += npart[((long)c * NKV + h) * HD + j];
  long o = (long)h * HD * HD + (long)r * HD + j;
  outn[o] = norm[o] + cs;
}

// ---------------- host ----------------
// Aliased arena (stream-serialized), same map as rounds 2-6 (peak 154.5 MiB).

extern "C" void kernel_launch(void* const* d_in, const int* in_sizes, int n_in,
                              void* d_out, int out_size, void* d_ws, size_t ws_size,
                              hipStream_t stream) {
  const float* hs = (const float*)d_in[0];
  const int* pos = (const int*)d_in[1];
  const float* wq = (const float*)d_in[2];
  const float* wk = (const float*)d_in[3];
  const float* wv = (const float*)d_in[4];
  const float* wo = (const float*)d_in[5];
  const float* memf = (const float*)d_in[6];
  const float* normf = (const float*)d_in[7];
  const float* beta = (const float*)d_in[8];
  (void)in_sizes; (void)n_in; (void)out_size; (void)ws_size;

  float* out = (float*)d_out;
  float* out_mem = out + (long)S_LEN * HID_DIM;
  float* out_norm = out_mem + NKV * HD * HD;

  const size_t MB = 1u << 20;
  char* w = (char*)d_ws;
  u16* hsb    = (u16*)(w + 0);
  u16* qnb    = (u16*)(w + 0);
  u16* comb   = (u16*)(w + 0);
  float* dpart= (float*)(w + 0);
  float* npart= (float*)(w + 2 * MB);
  u16* wT6    = (u16*)(w + 16 * MB);
  u16* rawq   = (u16*)(w + 16 * MB);
  u16* woT    = (u16*)(w + 16 * MB);
  u16* rawk   = (u16*)(w + 48 * MB);
  u16* bc     = (u16*)(w + 57 * MB);
  u16* vtb    = (u16*)(w + 57 * MB + 512 * 1024);
  float* qkvf = (float*)(w + 66 * MB + 512 * 1024);
  float* attn = (float*)(w + 66 * MB + 512 * 1024);
  float* Ub   = (float*)(w + 114 * MB + 512 * 1024);
  float* knf  = (float*)(w + 122 * MB + 512 * 1024);
  u16* qrb    = (u16*)(w + 130 * MB + 512 * 1024);
  u16* krb    = (u16*)(w + 146 * MB + 512 * 1024);
  u16* knb    = (u16*)(w + 150 * MB + 512 * 1024);

  // --- A: conversions + fused QKV projection ---
  k_f32_to_bf16<<<dim3((S_LEN * HID_DIM / 4 + 255) / 256), dim3(256), 0, stream>>>(
      hs, hsb, (long)(S_LEN * HID_DIM / 4));
  k_tr64<<<dim3(64, 64, 1), dim3(256), 0, stream>>>(
      wq, wT6, HID_DIM, HID_DIM, 0L, 0L);
  k_tr64<<<dim3(16, 64, 1), dim3(256), 0, stream>>>(
      wk, wT6 + (long)HID_DIM * HID_DIM, 1024, HID_DIM, 0L, 0L);
  k_tr64<<<dim3(16, 64, 1), dim3(256), 0, stream>>>(
      wv, wT6 + (long)(HID_DIM + 1024) * HID_DIM, 1024, HID_DIM, 0L, 0L);
  k_gemm6<<<dim3(QKV_N / 256, S_LEN / 128, 1), dim3(512), 0, stream>>>(
      hsb, wT6, qkvf, HID_DIM, QKV_N, 0L, 0L, 0L, 1, 0);

  // --- D: qn + rope fused ---
  k_qnrope<<<dim3(S_LEN, NH + NKV), dim3(64), 0, stream>>>(
      qkvf, pos, qnb, qrb, knb, krb, knf);

  // --- E: V^T per kv head; bc = [mem^T | norm] bf16 ---
  k_tr64<<<dim3(2, 32, NKV), dim3(256), 0, stream>>>(
      qkvf + HID_DIM + NKV * HD, vtb, QKV_N, S_LEN, 128L, (long)(HD * S_LEN));
  k_tr64<<<dim3(2, 2, NKV), dim3(256), 0, stream>>>(
      memf, bc, HD, HD, (long)(HD * HD), (long)(256 * HD));
  k_norm_to_bc<<<dim3(64, NKV), dim3(256), 0, stream>>>(normf, bc);

  // --- F: retrieval raws (batched, bf16 out) ---
  k_gemm6<<<dim3(1, 16, NH), dim3(512), 0, stream>>>(
      qnb, bc, rawq, HD, 256, (long)(S_LEN * HD), (long)(256 * HD),
      (long)(S_LEN * 256), NKV, 1);
  k_gemm6<<<dim3(1, 16, NKV), dim3(512), 0, stream>>>(
      knb, bc, rawk, HD, 256, (long)(S_LEN * HD), (long)(256 * HD),
      (long)(S_LEN * 256), NKV, 1);

  // --- G: U = v - v_ret ---
  k_uvret<<<dim3(S_LEN, NKV), dim3(128), 0, stream>>>(rawk, qkvf, Ub);

  // --- H: attention ---
  k_flash3<<<dim3(16, NH), dim3(256), 0, stream>>>(qrb, krb, vtb, attn);

  // --- I: combine ---
  k_combine<<<dim3(S_LEN, NH), dim3(128), 0, stream>>>(rawq, attn, beta, comb);

  // --- J: wo^T; output projection ---
  k_tr64<<<dim3(64, 64, 1), dim3(256), 0, stream>>>(
      wo, woT, HID_DIM, HID_DIM, 0L, 0L);
  k_gemm6<<<dim3(HID_DIM / 256, S_LEN / 128, 1), dim3(512), 0, stream>>>(
      comb, woT, out, HID_DIM, HID_DIM, 0L, 0L, 0L, 1, 0);

  // --- K: memory / norm updates ---
  k_delta_part<<<dim3(8, NKV, 4), dim3(128), 0, stream>>>(knf, Ub, dpart);
  k_delta_reduce<<<dim3(512), dim3(256), 0, stream>>>(dpart, memf, out_mem);
  k_norm_part<<<dim3(16, NKV), dim3(128), 0, stream>>>(knf, npart);
  k_norm_write<<<dim3(NKV, 64), dim3(256), 0, stream>>>(npart, normf, out_norm);
}

// Round 8
// 435.126 us; speedup vs baseline: 1.0978x; 1.0278x over previous
//
#include <hip/hip_runtime.h>

#define S_LEN 2048
#define HID_DIM 4096
#define NH 32
#define NKV 8
#define HD 128
#define QKV_N 6144
#define SCALE_F 0.08838834764831845f

typedef unsigned short u16;
typedef __attribute__((ext_vector_type(8))) __bf16 bf16x8;
typedef __attribute__((ext_vector_type(4))) float f32x4;

__device__ __forceinline__ u16 f2bf(float f) {
  unsigned u = __float_as_uint(f);
  return (u16)((u + 0x7fffu + ((u >> 16) & 1u)) >> 16);
}
__device__ __forceinline__ float bf2f(u16 v) {
  return __uint_as_float((unsigned)v << 16);
}

__device__ __forceinline__ void gl_lds16(const u16* g, u16* l) {
  __builtin_amdgcn_global_load_lds(
      (const __attribute__((address_space(1))) unsigned int*)g,
      (__attribute__((address_space(3))) unsigned int*)l, 16, 0, 0);
}

// ---------------- elementwise / layout kernels ----------------

__global__ void k_f32_to_bf16(const float* __restrict__ in, u16* __restrict__ out, long n4) {
  long i = (long)blockIdx.x * blockDim.x + threadIdx.x;
  if (i >= n4) return;
  float4 v = ((const float4*)in)[i];
  ushort4 o;
  o.x = f2bf(v.x); o.y = f2bf(v.y); o.z = f2bf(v.z); o.w = f2bf(v.w);
  ((ushort4*)out)[i] = o;
}

__global__ void k_tr64(const float* __restrict__ in, u16* __restrict__ out,
                       int ld_in, int ld_out, long in_bs, long out_bs) {
  __shared__ float tile[64][65];
  const float* A = in + (long)blockIdx.z * in_bs;
  u16* O = out + (long)blockIdx.z * out_bs;
  int r0 = blockIdx.y * 64, c0 = blockIdx.x * 64;
  int tx = threadIdx.x & 31, ty = threadIdx.x >> 5;
#pragma unroll
  for (int i = 0; i < 8; i++) {
    int r = ty + 8 * i;
    float2 v = *(const float2*)&A[(long)(r0 + r) * ld_in + c0 + 2 * tx];
    tile[r][2 * tx] = v.x;
    tile[r][2 * tx + 1] = v.y;
  }
  __syncthreads();
#pragma unroll
  for (int i = 0; i < 8; i++) {
    int c = ty + 8 * i;
    ushort2 o;
    o.x = f2bf(tile[2 * tx][c]);
    o.y = f2bf(tile[2 * tx + 1][c]);
    *(ushort2*)&O[(long)(c0 + c) * ld_out + r0 + 2 * tx] = o;
  }
}

__global__ void k_norm_to_bc(const float* __restrict__ norm, u16* __restrict__ bc) {
  int h = blockIdx.y;
  int i = blockIdx.x * 256 + threadIdx.x;
  bc[(long)h * 32768 + 16384 + i] = f2bf(norm[(long)h * 16384 + i]);
}

// ---------------- GEMM v8: m201-style 8-phase 256x256, BK=64 ----------------
// 512 thr (8 waves = 2M x 4N, per-wave 128x64). 2 LDS dbufs (128 KiB total);
// iteration computes K-tiles u0=2t (dbuf0, phases 0-3) and u1=2t+1 (dbuf1,
// phases 4-7). Each phase: {frag ds_reads | one half-tile stage (2 gl_lds) |
// fence barrier | setprio(1) 16 MFMA setprio(0) | fence barrier}.
// Stage schedule (half = 2 gl_lds of 64 rows each):
//   ph0: d1.A rows 0-127   (tile u1)    ph4: d0.A rows 0-127 (u0+2, if st0)
//   ph1: d1.A rows 128-255 (tile u1)    ph5: d0.A rows 128-255
//   ph2: d0.B rows 0-127   (u0+2, st0)  ph6: d1.B rows 0-127 (u1+2, if st1)
//   ph3: d0.B rows 128-255; vmcnt(4)    ph7: d1.B rows 128-255; vmcnt(4)
// Safety: every overwrite is >=1 phase-barrier after the last read of that
// region; vmcnt(4) at ph3 guarantees d1 (read ph4) landed (only ph2/ph3's
// d0.B may be outstanding); vmcnt(4) at ph7 guarantees d0 (read next ph0)
// landed. Last iteration: ph3 uses vmcnt(0), ph7 skips, stages for tiles
// >= KT skipped. Swizzle: 16B-colblock ^= row&7 (pre-swizzled source, same
// XOR on ds_read) -> 2-way bank aliasing (free).

__global__ __launch_bounds__(512, 2) void k_gemm8(
    const u16* __restrict__ A, const u16* __restrict__ Bt, void* __restrict__ Cv,
    int kloop, int lda, int ldb, int ldc,
    long strideA, long strideB, long strideC, int bmodB, int obf) {
  __shared__ __align__(16) u16 lds[65536];  // dbuf d at d*32768: A[256][64], B[256][64]
  const int bz = blockIdx.z;
  const u16* Ap = A + (long)bz * strideA;
  const u16* Bp = Bt + (long)(bz % bmodB) * strideB;
  const long coff = (long)bz * strideC;

  const int gx = gridDim.x, gy = gridDim.y;
  const int nwg = gx * gy;
  int id = blockIdx.y * gx + blockIdx.x;
  if (!(nwg & 7)) { int q = nwg >> 3; id = (id & 7) * q + (id >> 3); }
  const int m0 = (id % gy) * 256;   // m-fastest within XCD chunk
  const int n0 = (id / gy) * 256;

  const int tid = threadIdx.x, wid = tid >> 6, lane = tid & 63;
  const int l15 = lane & 15, lhi = lane >> 4;
  const int wm = wid >> 2, wn = wid & 3;  // per-wave 128 rows x 64 cols

  // stage addressing: issue g covers rows g*64 + wid*8 + (lane>>3), block lane&7
  const int srow = (wid << 3) + (lane >> 3);
  const int ssw = ((lane & 7) ^ (lane >> 3)) * 8;  // pre-swizzled source col
  auto stA = [&](int d, int g, long kt) {
    gl_lds16(Ap + (long)(m0 + g * 64 + srow) * lda + kt + ssw,
             &lds[d * 32768 + (g * 64 + (wid << 3)) * 64]);
  };
  auto stB = [&](int d, int g, long kt) {
    gl_lds16(Bp + (long)(n0 + g * 64 + srow) * ldb + kt + ssw,
             &lds[d * 32768 + 16384 + (g * 64 + (wid << 3)) * 64]);
  };

  // ds_read fragment addressing (swizzled)
  const int swb = l15 & 7;
  const int aBase = (wm * 128 + l15) * 64;          // + mi*1024 + ko
  const int bBase = 16384 + (wn * 64 + l15) * 64;   // + ni*1024 + ko
  const int ko0 = (lhi ^ swb) * 8;
  const int ko1 = ((4 + lhi) ^ swb) * 8;

  const int KT = kloop >> 6;   // K-tiles (even)
  const int NIT = KT >> 1;

  f32x4 acc[8][4];
#pragma unroll
  for (int i = 0; i < 8; i++)
#pragma unroll
    for (int j = 0; j < 4; j++) acc[i][j] = (f32x4){0.f, 0.f, 0.f, 0.f};

  // prologue: d0 = tile 0 (A+B), d1.B = tile 1
#pragma unroll
  for (int g = 0; g < 4; g++) stA(0, g, 0);
#pragma unroll
  for (int g = 0; g < 4; g++) stB(0, g, 0);
#pragma unroll
  for (int g = 0; g < 4; g++) stB(1, g, 64);
  asm volatile("s_waitcnt vmcnt(4)" ::: "memory");
  __builtin_amdgcn_s_barrier();
  asm volatile("" ::: "memory");

  for (int t = 0; t < NIT; ++t) {
    const long kA = (long)(2 * t + 1) * 64;
    const long kB0 = (long)(2 * t + 2) * 64;
    const long kB1 = (long)(2 * t + 3) * 64;
    const bool st0 = (2 * t + 2) < KT;
    const bool st1 = (2 * t + 3) < KT;
    const bool last = (t + 1 == NIT);

    // ---- phases 0-3: compute dbuf0 (tile u0) ----
    {
      const u16* lb = &lds[0];
      bf16x8 Bf[4][2];
#pragma unroll
      for (int p = 0; p < 4; p++) {
        if (p == 0) {
#pragma unroll
          for (int ni = 0; ni < 4; ni++) {
            Bf[ni][0] = *(const bf16x8*)&lb[bBase + ni * 1024 + ko0];
            Bf[ni][1] = *(const bf16x8*)&lb[bBase + ni * 1024 + ko1];
          }
        }
        bf16x8 a0k0 = *(const bf16x8*)&lb[aBase + (2 * p) * 1024 + ko0];
        bf16x8 a0k1 = *(const bf16x8*)&lb[aBase + (2 * p) * 1024 + ko1];
        bf16x8 a1k0 = *(const bf16x8*)&lb[aBase + (2 * p + 1) * 1024 + ko0];
        bf16x8 a1k1 = *(const bf16x8*)&lb[aBase + (2 * p + 1) * 1024 + ko1];
        if (p == 0) { stA(1, 0, kA); stA(1, 1, kA); }
        else if (p == 1) { stA(1, 2, kA); stA(1, 3, kA); }
        else if (p == 2) { if (st0) { stB(0, 0, kB0); stB(0, 1, kB0); } }
        else { if (st0) { stB(0, 2, kB0); stB(0, 3, kB0); } }
        asm volatile("" ::: "memory");
        if (p == 3) {
          if (last) asm volatile("s_waitcnt vmcnt(0)" ::: "memory");
          else      asm volatile("s_waitcnt vmcnt(4)" ::: "memory");
        }
        __builtin_amdgcn_s_barrier();
        asm volatile("" ::: "memory");
        __builtin_amdgcn_s_setprio(1);
#pragma unroll
        for (int ni = 0; ni < 4; ni++) {
          acc[2 * p][ni] = __builtin_amdgcn_mfma_f32_16x16x32_bf16(a0k0, Bf[ni][0], acc[2 * p][ni], 0, 0, 0);
          acc[2 * p][ni] = __builtin_amdgcn_mfma_f32_16x16x32_bf16(a0k1, Bf[ni][1], acc[2 * p][ni], 0, 0, 0);
          acc[2 * p + 1][ni] = __builtin_amdgcn_mfma_f32_16x16x32_bf16(a1k0, Bf[ni][0], acc[2 * p + 1][ni], 0, 0, 0);
          acc[2 * p + 1][ni] = __builtin_amdgcn_mfma_f32_16x16x32_bf16(a1k1, Bf[ni][1], acc[2 * p + 1][ni], 0, 0, 0);
        }
        __builtin_amdgcn_s_setprio(0);
        asm volatile("" ::: "memory");
        __builtin_amdgcn_s_barrier();
        asm volatile("" ::: "memory");
      }
    }
    // ---- phases 4-7: compute dbuf1 (tile u1) ----
    {
      const u16* lb = &lds[32768];
      bf16x8 Bf[4][2];
#pragma unroll
      for (int p = 0; p < 4; p++) {
        if (p == 0) {
#pragma unroll
          for (int ni = 0; ni < 4; ni++) {
            Bf[ni][0] = *(const bf16x8*)&lb[bBase + ni * 1024 + ko0];
            Bf[ni][1] = *(const bf16x8*)&lb[bBase + ni * 1024 + ko1];
          }
        }
        bf16x8 a0k0 = *(const bf16x8*)&lb[aBase + (2 * p) * 1024 + ko0];
        bf16x8 a0k1 = *(const bf16x8*)&lb[aBase + (2 * p) * 1024 + ko1];
        bf16x8 a1k0 = *(const bf16x8*)&lb[aBase + (2 * p + 1) * 1024 + ko0];
        bf16x8 a1k1 = *(const bf16x8*)&lb[aBase + (2 * p + 1) * 1024 + ko1];
        if (p == 0) { if (st0) { stA(0, 0, kB0); stA(0, 1, kB0); } }
        else if (p == 1) { if (st0) { stA(0, 2, kB0); stA(0, 3, kB0); } }
        else if (p == 2) { if (st1) { stB(1, 0, kB1); stB(1, 1, kB1); } }
        else { if (st1) { stB(1, 2, kB1); stB(1, 3, kB1); } }
        asm volatile("" ::: "memory");
        if (p == 3 && !last) asm volatile("s_waitcnt vmcnt(4)" ::: "memory");
        __builtin_amdgcn_s_barrier();
        asm volatile("" ::: "memory");
        __builtin_amdgcn_s_setprio(1);
#pragma unroll
        for (int ni = 0; ni < 4; ni++) {
          acc[2 * p][ni] = __builtin_amdgcn_mfma_f32_16x16x32_bf16(a0k0, Bf[ni][0], acc[2 * p][ni], 0, 0, 0);
          acc[2 * p][ni] = __builtin_amdgcn_mfma_f32_16x16x32_bf16(a0k1, Bf[ni][1], acc[2 * p][ni], 0, 0, 0);
          acc[2 * p + 1][ni] = __builtin_amdgcn_mfma_f32_16x16x32_bf16(a1k0, Bf[ni][0], acc[2 * p + 1][ni], 0, 0, 0);
          acc[2 * p + 1][ni] = __builtin_amdgcn_mfma_f32_16x16x32_bf16(a1k1, Bf[ni][1], acc[2 * p + 1][ni], 0, 0, 0);
        }
        __builtin_amdgcn_s_setprio(0);
        asm volatile("" ::: "memory");
        __builtin_amdgcn_s_barrier();
        asm volatile("" ::: "memory");
      }
    }
  }

#pragma unroll
  for (int mi = 0; mi < 8; mi++)
#pragma unroll
    for (int ni = 0; ni < 4; ni++)
#pragma unroll
      for (int j = 0; j < 4; j++) {
        long row = m0 + wm * 128 + mi * 16 + lhi * 4 + j;
        long col = n0 + wn * 64 + ni * 16 + l15;
        if (obf)
          ((u16*)Cv)[coff + row * ldc + col] = f2bf(acc[mi][ni][j]);
        else
          ((float*)Cv)[coff + row * ldc + col] = acc[mi][ni][j];
      }
}

// ---------------- split-K add epilogue: out = p0 + p1 (bf16 partials) ----------------

__global__ void k_addp(const u16* __restrict__ p0, const u16* __restrict__ p1,
                       float* __restrict__ out) {
  long i = ((long)blockIdx.x * 256 + threadIdx.x) * 8;
  ushort4 a0 = *(const ushort4*)&p0[i], a1 = *(const ushort4*)&p0[i + 4];
  ushort4 b0 = *(const ushort4*)&p1[i], b1 = *(const ushort4*)&p1[i + 4];
  float4 o0, o1;
  o0.x = bf2f(a0.x) + bf2f(b0.x); o0.y = bf2f(a0.y) + bf2f(b0.y);
  o0.z = bf2f(a0.z) + bf2f(b0.z); o0.w = bf2f(a0.w) + bf2f(b0.w);
  o1.x = bf2f(a1.x) + bf2f(b1.x); o1.y = bf2f(a1.y) + bf2f(b1.y);
  o1.z = bf2f(a1.z) + bf2f(b1.z); o1.w = bf2f(a1.w) + bf2f(b1.w);
  *(float4*)&out[i] = o0;
  *(float4*)&out[i + 4] = o1;
}

// ---------------- fused qn + rope ----------------

__global__ void k_qnrope(const float* __restrict__ qkv, const int* __restrict__ pos,
                         u16* __restrict__ qnb, u16* __restrict__ qrb,
                         u16* __restrict__ knb, u16* __restrict__ krb,
                         float* __restrict__ knf) {
  int s = blockIdx.x, y = blockIdx.y, l = threadIdx.x;  // 64 threads
  bool isq = y < NH;
  int h = isq ? y : y - NH;
  const float* row = qkv + (long)s * QKV_N + (isq ? h * HD : HID_DIM + h * HD);
  float x0 = row[l], x1 = row[l + 64];
  float f0 = x0 > 0.f ? x0 + 1.f : __expf(x0);
  float f1 = x1 > 0.f ? x1 + 1.f : __expf(x1);
  float sum = f0 + f1;
#pragma unroll
  for (int m = 32; m >= 1; m >>= 1) sum += __shfl_xor(sum, m);
  float inv = 1.f / (sum + 1e-8f);
  float y0 = f0 * inv, y1 = f1 * inv;
  long o = ((long)h * S_LEN + s) * HD;
  float p = (float)pos[s];
  float ang = p * expf(-(float)l * (9.210340371976184f / 64.0f));
  float c = cosf(ang), sn = sinf(ang);
  u16 r0 = f2bf(x0 * c - x1 * sn), r1 = f2bf(x1 * c + x0 * sn);
  if (isq) {
    qnb[o + l] = f2bf(y0); qnb[o + l + 64] = f2bf(y1);
    qrb[o + l] = r0; qrb[o + l + 64] = r1;
  } else {
    knb[o + l] = f2bf(y0); knb[o + l + 64] = f2bf(y1);
    knf[o + l] = y0; knf[o + l + 64] = y1;
    krb[o + l] = r0; krb[o + l + 64] = r1;
  }
}

// ---------------- U = v - v_ret ----------------

__global__ void k_uvret(const u16* __restrict__ rawk, const float* __restrict__ qkv,
                        float* __restrict__ U) {
  int s = blockIdx.x, h = blockIdx.y, e = threadIdx.x;  // 128 threads
  long base = ((long)h * S_LEN + s) * 256;
  float num = bf2f(rawk[base + e]), den = bf2f(rawk[base + 128 + e]);
  U[((long)h * S_LEN + s) * HD + e] =
      qkv[(long)s * QKV_N + HID_DIM + NKV * HD + h * HD + e] - num / (den + 1e-8f);
}

// ---------------- flash attention v3 ----------------

__global__ __launch_bounds__(256, 2) void k_flash3(
    const u16* __restrict__ qr, const u16* __restrict__ kr,
    const u16* __restrict__ vt, float* __restrict__ attn) {
  __shared__ u16 KV[2][16384];
  __shared__ u16 Ps[4][16 * 64];
  const int bx = blockIdx.x, h = blockIdx.y;
  const int hk = h >> 2;
  const int tid = threadIdx.x, wid = tid >> 6, lane = tid & 63;
  const int l15 = lane & 15, lhi = lane >> 4;
  const u16* qbase = qr + (long)h * S_LEN * HD;
  const u16* kb0 = kr + (long)hk * S_LEN * HD;
  const u16* vb0 = vt + (long)hk * HD * S_LEN;
  float* ob = attn + (long)h * S_LEN * HD;
  u16* P = Ps[wid];

  int kr_r[4], kr_sc[4], vr_r[4], vr_sc[4];
#pragma unroll
  for (int it = 0; it < 4; it++) {
    int chunk = it * 4 + wid;
    kr_r[it] = chunk * 4 + (lane >> 4);
    kr_sc[it] = ((lane & 15) * 8) ^ ((kr_r[it] & 7) * 8);
    vr_r[it] = chunk * 8 + (lane >> 3);
    vr_sc[it] = ((lane & 7) * 8) ^ ((vr_r[it] & 7) * 8);
  }

  for (int si = 0; si < 2; si++) {
    const int s = si ? (31 - bx) : bx;
    const int qs = s * 64 + wid * 16;
    bf16x8 aq[4];
#pragma unroll
    for (int kc = 0; kc < 4; kc++)
      aq[kc] = *(const bf16x8*)&qbase[(long)(qs + l15) * HD + kc * 32 + lhi * 8];
    f32x4 accO[8];
#pragma unroll
    for (int i = 0; i < 8; i++) accO[i] = (f32x4){0.f, 0.f, 0.f, 0.f};
    float rs[4] = {0.f, 0.f, 0.f, 0.f};

    if (si) __syncthreads();
    {
      u16* Kb = KV[0];
#pragma unroll
      for (int it = 0; it < 4; it++)
        gl_lds16(kb0 + (long)kr_r[it] * HD + kr_sc[it], &Kb[(it * 4 + wid) * 512]);
#pragma unroll
      for (int it = 0; it < 4; it++)
        gl_lds16(vb0 + (long)vr_r[it] * S_LEN + vr_sc[it], &Kb[8192 + (it * 4 + wid) * 512]);
    }
    int cur = 0;

    for (int t = 0; t <= s; t++) {
      asm volatile("s_waitcnt vmcnt(0)" ::: "memory");
      __syncthreads();
      if (t < s) {
        u16* Kb = KV[cur ^ 1];
        const long kt = (long)(t + 1) * 64;
#pragma unroll
        for (int it = 0; it < 4; it++)
          gl_lds16(kb0 + (kt + kr_r[it]) * HD + kr_sc[it], &Kb[(it * 4 + wid) * 512]);
#pragma unroll
        for (int it = 0; it < 4; it++)
          gl_lds16(vb0 + (long)vr_r[it] * S_LEN + kt + vr_sc[it], &Kb[8192 + (it * 4 + wid) * 512]);
      }
      const u16* Ks = KV[cur];
      const u16* Vs = Ks + 8192;

      f32x4 accS[4];
#pragma unroll
      for (int i = 0; i < 4; i++) accS[i] = (f32x4){0.f, 0.f, 0.f, 0.f};
#pragma unroll
      for (int ni = 0; ni < 4; ni++) {
        int row = ni * 16 + l15;
#pragma unroll
        for (int kc = 0; kc < 4; kc++) {
          bf16x8 bk = *(const bf16x8*)&Ks[row * 128 + ((kc * 32 + lhi * 8) ^ ((row & 7) * 8))];
          accS[ni] = __builtin_amdgcn_mfma_f32_16x16x32_bf16(aq[kc], bk, accS[ni], 0, 0, 0);
        }
      }
      const bool diag = (t == s);
#pragma unroll
      for (int ni = 0; ni < 4; ni++) {
        int col = t * 64 + ni * 16 + l15;
#pragma unroll
        for (int j = 0; j < 4; j++) {
          int row = qs + lhi * 4 + j;
          float p = (!diag || col <= row) ? __expf(accS[ni][j] * SCALE_F) : 0.f;
          rs[j] += p;
          int pr = lhi * 4 + j;
          P[pr * 64 + ((ni * 16 + l15) ^ ((pr & 7) * 8))] = f2bf(p);
        }
      }
      asm volatile("s_waitcnt lgkmcnt(0)" ::: "memory");
      __builtin_amdgcn_sched_barrier(0);
      bf16x8 ap[2];
#pragma unroll
      for (int ks = 0; ks < 2; ks++)
        ap[ks] = *(const bf16x8*)&P[l15 * 64 + ((ks * 32 + lhi * 8) ^ ((l15 & 7) * 8))];
#pragma unroll
      for (int nj = 0; nj < 8; nj++) {
        int row = nj * 16 + l15;
#pragma unroll
        for (int ks = 0; ks < 2; ks++) {
          bf16x8 bv = *(const bf16x8*)&Vs[row * 64 + ((ks * 32 + lhi * 8) ^ ((row & 7) * 8))];
          accO[nj] = __builtin_amdgcn_mfma_f32_16x16x32_bf16(ap[ks], bv, accO[nj], 0, 0, 0);
        }
      }
      cur ^= 1;
    }
#pragma unroll
    for (int j = 0; j < 4; j++) {
      float v = rs[j];
      v += __shfl_xor(v, 1);
      v += __shfl_xor(v, 2);
      v += __shfl_xor(v, 4);
      v += __shfl_xor(v, 8);
      rs[j] = 1.f / v;
    }
#pragma unroll
    for (int nj = 0; nj < 8; nj++)
#pragma unroll
      for (int j = 0; j < 4; j++)
        ob[(long)(qs + lhi * 4 + j) * HD + nj * 16 + l15] = accO[nj][j] * rs[j];
  }
}

// ---------------- combine ----------------

__global__ void k_combine(const u16* __restrict__ rawq, const float* __restrict__ attn,
                          const float* __restrict__ beta, u16* __restrict__ comb) {
  int s = blockIdx.x, h = blockIdx.y, d = threadIdx.x;  // 128 threads
  float g = 1.f / (1.f + __expf(-beta[0]));
  long b = ((long)h * S_LEN + s) * 256;
  float mo = bf2f(rawq[b + d]) / (bf2f(rawq[b + 128 + d]) + 1e-8f);
  float ao = attn[((long)h * S_LEN + s) * HD + d];
  comb[(long)s * HID_DIM + h * HD + d] = f2bf(g * mo + (1.f - g) * ao);
}

// ---------------- delta-rule memory / norm updates (f32 exact path) ----------------

__global__ void k_delta_part(const float* __restrict__ knf, const float* __restrict__ U,
                             float* __restrict__ dpart) {
  int d0 = blockIdx.x * 16, h = blockIdx.y, c = blockIdx.z, e = threadIdx.x;
  const float* kh = knf + (long)h * S_LEN * HD + (long)c * 512 * HD;
  const float* Uh = U + (long)h * S_LEN * HD + (long)c * 512 * HD;
  float a[16];
#pragma unroll
  for (int d = 0; d < 16; d++) a[d] = 0.f;
  for (int s = 0; s < 512; s++) {
    float u = Uh[(long)s * HD + e];
    const float* kr = &kh[(long)s * HD + d0];
#pragma unroll
    for (int d = 0; d < 16; d++) a[d] += kr[d] * u;
  }
  long ob = (long)c * (NKV * HD * HD) + (long)h * HD * HD + (long)d0 * HD + e;
#pragma unroll
  for (int d = 0; d < 16; d++) dpart[ob + (long)d * HD] = a[d];
}

__global__ void k_delta_reduce(const float* __restrict__ dpart, const float* __restrict__ mem,
                               float* __restrict__ outmem) {
  long i = (long)blockIdx.x * 256 + threadIdx.x;  // 131072
  const long N = (long)NKV * HD * HD;
  float a = dpart[i] + dpart[N + i] + dpart[2 * N + i] + dpart[3 * N + i];
  outmem[i] = mem[i] + a;
}

__global__ void k_norm_part(const float* __restrict__ knf, float* __restrict__ npart) {
  int c = blockIdx.x, h = blockIdx.y, j = threadIdx.x;
  const float* kh = knf + (long)h * S_LEN * HD + (long)c * 128 * HD;
  float a = 0.f;
  for (int s = 0; s < 128; s++) a += kh[(long)s * HD + j];
  npart[((long)c * NKV + h) * HD + j] = a;
}

__global__ void k_norm_write(const float* __restrict__ npart, const float* __restrict__ norm,
                             float* __restrict__ outn) {
  int h = blockIdx.x, j = threadIdx.x & 127;
  int r = blockIdx.y * 2 + (threadIdx.x >> 7);
  float cs = 0.f;
#pragma unroll
  for (int c = 0; c < 16; c++) cs += npart[((long)c * NKV + h) * HD + j];
  long o = (long)h * HD * HD + (long)r * HD + j;
  outn[o] = norm[o] + cs;
}

// ---------------- host ----------------
// Arena additions: p0 (u16 16MiB) at [98.5,114.5) (attn tail region, free at J);
// p1 (u16 16MiB) at [130.5,146.5) (qrb region, free after flash).

extern "C" void kernel_launch(void* const* d_in, const int* in_sizes, int n_in,
                              void* d_out, int out_size, void* d_ws, size_t ws_size,
                              hipStream_t stream) {
  const float* hs = (const float*)d_in[0];
  const int* pos = (const int*)d_in[1];
  const float* wq = (const float*)d_in[2];
  const float* wk = (const float*)d_in[3];
  const float* wv = (const float*)d_in[4];
  const float* wo = (const float*)d_in[5];
  const float* memf = (const float*)d_in[6];
  const float* normf = (const float*)d_in[7];
  const float* beta = (const float*)d_in[8];
  (void)in_sizes; (void)n_in; (void)out_size; (void)ws_size;

  float* out = (float*)d_out;
  float* out_mem = out + (long)S_LEN * HID_DIM;
  float* out_norm = out_mem + NKV * HD * HD;

  const size_t MB = 1u << 20;
  char* w = (char*)d_ws;
  u16* hsb    = (u16*)(w + 0);
  u16* qnb    = (u16*)(w + 0);
  u16* comb   = (u16*)(w + 0);
  float* dpart= (float*)(w + 0);
  float* npart= (float*)(w + 2 * MB);
  u16* wT6    = (u16*)(w + 16 * MB);
  u16* rawq   = (u16*)(w + 16 * MB);
  u16* woT    = (u16*)(w + 16 * MB);
  u16* rawk   = (u16*)(w + 48 * MB);
  u16* bc     = (u16*)(w + 57 * MB);
  u16* vtb    = (u16*)(w + 57 * MB + 512 * 1024);
  float* qkvf = (float*)(w + 66 * MB + 512 * 1024);
  float* attn = (float*)(w + 66 * MB + 512 * 1024);
  u16* p0     = (u16*)(w + 98 * MB + 512 * 1024);
  float* Ub   = (float*)(w + 114 * MB + 512 * 1024);
  float* knf  = (float*)(w + 122 * MB + 512 * 1024);
  u16* qrb    = (u16*)(w + 130 * MB + 512 * 1024);
  u16* p1     = (u16*)(w + 130 * MB + 512 * 1024);
  u16* krb    = (u16*)(w + 146 * MB + 512 * 1024);
  u16* knb    = (u16*)(w + 150 * MB + 512 * 1024);

  // --- A: conversions + fused QKV projection ---
  k_f32_to_bf16<<<dim3((S_LEN * HID_DIM / 4 + 255) / 256), dim3(256), 0, stream>>>(
      hs, hsb, (long)(S_LEN * HID_DIM / 4));
  k_tr64<<<dim3(64, 64, 1), dim3(256), 0, stream>>>(
      wq, wT6, HID_DIM, HID_DIM, 0L, 0L);
  k_tr64<<<dim3(16, 64, 1), dim3(256), 0, stream>>>(
      wk, wT6 + (long)HID_DIM * HID_DIM, 1024, HID_DIM, 0L, 0L);
  k_tr64<<<dim3(16, 64, 1), dim3(256), 0, stream>>>(
      wv, wT6 + (long)(HID_DIM + 1024) * HID_DIM, 1024, HID_DIM, 0L, 0L);
  k_gemm8<<<dim3(QKV_N / 256, S_LEN / 256, 1), dim3(512), 0, stream>>>(
      hsb, wT6, qkvf, HID_DIM, HID_DIM, HID_DIM, QKV_N, 0L, 0L, 0L, 1, 0);

  // --- D: qn + rope fused ---
  k_qnrope<<<dim3(S_LEN, NH + NKV), dim3(64), 0, stream>>>(
      qkvf, pos, qnb, qrb, knb, krb, knf);

  // --- E: V^T per kv head; bc = [mem^T | norm] bf16 ---
  k_tr64<<<dim3(2, 32, NKV), dim3(256), 0, stream>>>(
      qkvf + HID_DIM + NKV * HD, vtb, QKV_N, S_LEN, 128L, (long)(HD * S_LEN));
  k_tr64<<<dim3(2, 2, NKV), dim3(256), 0, stream>>>(
      memf, bc, HD, HD, (long)(HD * HD), (long)(256 * HD));
  k_norm_to_bc<<<dim3(64, NKV), dim3(256), 0, stream>>>(normf, bc);

  // --- F: retrieval raws (batched, bf16 out) ---
  k_gemm8<<<dim3(1, 8, NH), dim3(512), 0, stream>>>(
      qnb, bc, rawq, HD, HD, HD, 256, (long)(S_LEN * HD), (long)(256 * HD),
      (long)(S_LEN * 256), NKV, 1);
  k_gemm8<<<dim3(1, 8, NKV), dim3(512), 0, stream>>>(
      knb, bc, rawk, HD, HD, HD, 256, (long)(S_LEN * HD), (long)(256 * HD),
      (long)(S_LEN * 256), NKV, 1);

  // --- G: U = v - v_ret ---
  k_uvret<<<dim3(S_LEN, NKV), dim3(128), 0, stream>>>(rawk, qkvf, Ub);

  // --- H: attention ---
  k_flash3<<<dim3(16, NH), dim3(256), 0, stream>>>(qrb, krb, vtb, attn);

  // --- I: combine ---
  k_combine<<<dim3(S_LEN, NH), dim3(128), 0, stream>>>(rawq, attn, beta, comb);

  // --- J: wo^T; output projection (split-K2, bf16 partials + add) ---
  k_tr64<<<dim3(64, 64, 1), dim3(256), 0, stream>>>(
      wo, woT, HID_DIM, HID_DIM, 0L, 0L);
  k_gemm8<<<dim3(HID_DIM / 256, S_LEN / 256, 2), dim3(512), 0, stream>>>(
      comb, woT, p0, 2048, HID_DIM, HID_DIM, HID_DIM,
      2048L, 2048L, (long)(p1 - p0), 2, 1);
  k_addp<<<dim3(S_LEN * HID_DIM / 2048), dim3(256), 0, stream>>>(p0, p1, out);

  // --- K: memory / norm updates ---
  k_delta_part<<<dim3(8, NKV, 4), dim3(128), 0, stream>>>(knf, Ub, dpart);
  k_delta_reduce<<<dim3(512), dim3(256), 0, stream>>>(dpart, memf, out_mem);
  k_norm_part<<<dim3(16, NKV), dim3(128), 0, stream>>>(knf, npart);
  k_norm_write<<<dim3(NKV, 64), dim3(256), 0, stream>>>(npart, normf, out_norm);
}